// Round 11
// baseline (1197.928 us; speedup 1.0000x reference)
//
#include <hip/hip_runtime.h>
#include <hip/hip_fp16.h>

// N=1024, F=22, T=1000, H=64, gates 4H=256
// R11: barrier-free dataflow, NO stager: L0 loads x global->regs (depth-2
// prefetch, f32->f16 cvt in regs). 768 threads = 12 waves, 3/SIMD balanced:
//   waves 0-3 L2, 4-7 L1, 8-11 L0.
// Ring depth 8, unroll-8. Flags: [0..3]=L2, [4..7]=L1, [8..11]=L0, [12..15]=BIG.
// Tight (every tick): own-group >= t-1. Amortized (every 4, at t0):
//   L2: L1 >= t0+3
//   L1: L0 >= t0+3 && L2 >= t0-5
//   L0: L1 >= t0-5
// Input kt-tiles read & MFMA'd BEFORE sibling spin (cross-lead makes them old);
// only rec kt-tiles wait. Producer fence = s_waitcnt lgkmcnt(0) (DS in-order;
// vmcnt never drained -> x prefetch lives across ticks).
#define TT 1000
#define FF 22
#define HH 64
#define BB 4
#define NBLK 256
#define S0 112
#define S1 144
#define SL0 (4 * S0)
#define SL1 (4 * S1)

typedef _Float16 half8 __attribute__((ext_vector_type(8)));
typedef float float4v __attribute__((ext_vector_type(4)));

__device__ __forceinline__ float sigm(float v) {
    return __builtin_amdgcn_rcpf(1.0f + __expf(-v));
}
__device__ __forceinline__ float tanh_(float v) {
    return 1.0f - 2.0f * __builtin_amdgcn_rcpf(__expf(2.0f * v) + 1.0f);
}

__device__ __forceinline__ float sel4(const float4v a, int q) {
    float lo = (q & 2) ? a[2] : a[0];
    float hi = (q & 2) ? a[3] : a[1];
    return (q & 1) ? hi : lo;
}

__device__ __forceinline__ float gate_update(const float z[4], float& c) {
    float cc = sigm(z[1]) * c + sigm(z[0]) * tanh_(z[2]);
    c = cc;
    return sigm(z[3]) * tanh_(cc);
}

__device__ __forceinline__ int ldmin4(const int* p) {
    int4 v = *(const int4*)p;
    return min(min(v.x, v.y), min(v.z, v.w));
}

#define SPIN(cond) do { for (;;) { asm volatile("" ::: "memory"); if (cond) break; \
                        __builtin_amdgcn_s_sleep(1); } asm volatile("" ::: "memory"); } while (0)
// DS-only fence: orders prior ds_writes before the following flag ds_write.
#define DSFENCE() asm volatile("s_waitcnt lgkmcnt(0)" ::: "memory")

extern "C" __global__ void __launch_bounds__(768, 1)
lstm_fused(const float* __restrict__ x,
           const float* __restrict__ Wih0, const float* __restrict__ Whh0,
           const float* __restrict__ bih0, const float* __restrict__ bhh0,
           const float* __restrict__ Wih1, const float* __restrict__ Whh1,
           const float* __restrict__ bih1, const float* __restrict__ bhh1,
           const float* __restrict__ Wih2, const float* __restrict__ Whh2,
           const float* __restrict__ bih2, const float* __restrict__ bhh2,
           const float* __restrict__ w0, const float* __restrict__ b0,
           const float* __restrict__ w1, const float* __restrict__ b1,
           const float* __restrict__ w2, const float* __restrict__ b2,
           const float* __restrict__ w3, const float* __restrict__ b3,
           const float* __restrict__ g0, const float* __restrict__ be0,
           const float* __restrict__ m0, const float* __restrict__ v0,
           const float* __restrict__ g1, const float* __restrict__ be1,
           const float* __restrict__ m1, const float* __restrict__ v1,
           const float* __restrict__ g2, const float* __restrict__ be2,
           const float* __restrict__ m2, const float* __restrict__ v2,
           float* __restrict__ out)
{
    __shared__ __align__(16) _Float16 in0[8 * SL0];
    __shared__ __align__(16) _Float16 in1[8 * SL1];
    __shared__ __align__(16) _Float16 in2[8 * SL1];
    __shared__ __align__(16) int flags[16];
    __shared__ float fcA[BB * 64];
    __shared__ float fcB[BB * 64];
    __shared__ float fcW[54 * 65];
    __shared__ float fcP[5 * 64];

    const int tid  = threadIdx.x;
    const int wv   = tid >> 6;      // 0..11
    const int role = wv >> 2;       // 0=L2, 1=L1, 2=L0
    const int w4   = wv & 3;
    const int l    = tid & 63;
    const int q    = l >> 4;
    const int l15  = l & 15;
    const int u    = 16 * w4 + l15;
    const int b    = q;
    const int n0   = blockIdx.x * BB;

    for (int i = tid; i < 8 * SL0; i += 768) in0[i] = (_Float16)0.0f;
    for (int i = tid; i < 8 * SL1; i += 768) in1[i] = (_Float16)0.0f;
    for (int i = tid; i < 8 * SL1; i += 768) in2[i] = (_Float16)0.0f;
    if (tid < 16) flags[tid] = (tid >= 12) ? (1 << 29) : -1;

    // ---- weight B-fragments: one unit per wave ----
    half8 wf[4][4];
    float4v biasC[4];
    if (role == 2) {                 // layer 0
#pragma unroll
        for (int g = 0; g < 4; ++g) {
            const int row = 64 * g + u;
#pragma unroll
            for (int kt = 0; kt < 3; ++kt) {
                half8 h{};
#pragma unroll
                for (int j = 0; j < 8; ++j) {
                    const int k = 32 * kt + 8 * q + j;
                    float val = 0.0f;
                    if (k < 32) { if (k < FF) val = Wih0[row * FF + k]; }
                    else        { val = Whh0[row * HH + (k - 32)]; }
                    h[j] = (_Float16)val;
                }
                wf[g][kt] = h;
            }
            float bv = bih0[row] + bhh0[row];
            biasC[g] = float4v{bv, bv, bv, bv};
        }
    } else {                         // 0 -> layer 2, 1 -> layer 1
        const float* Wih = role ? Wih1 : Wih2;
        const float* Whh = role ? Whh1 : Whh2;
        const float* bih = role ? bih1 : bih2;
        const float* bhh = role ? bhh1 : bhh2;
#pragma unroll
        for (int g = 0; g < 4; ++g) {
            const int row = 64 * g + u;
#pragma unroll
            for (int kt = 0; kt < 4; ++kt) {
                half8 h{};
#pragma unroll
                for (int j = 0; j < 8; ++j) {
                    const int k = 32 * kt + 8 * q + j;
                    h[j] = (_Float16)((k < 64) ? Wih[row * HH + k] : Whh[row * HH + (k - 64)]);
                }
                wf[g][kt] = h;
            }
            float bv = bih[row] + bhh[row];
            biasC[g] = float4v{bv, bv, bv, bv};
        }
    }

    volatile int* vfl = (volatile int*)flags;
    __syncthreads();

    const int arow = (role == 2) ? ((l15 & 3) * S0 + q * 8) : ((l15 & 3) * S1 + q * 8);
    float c = 0.f;

    if (role == 2) {                   // ===== L0: x from global, depth-2 reg prefetch =====
        const int rrow = l15 & 3;
        const float* xbase = x + (size_t)(n0 + rrow) * FF * TT;
        float xA[8], xB[8];
        // lane's features: f = 8q+j (valid f < 22)
#define LDX(tt, buf) do { _Pragma("unroll") \
        for (int j = 0; j < 8; ++j) { \
            const int f = 8 * q + j; \
            (buf)[j] = (f < FF) ? xbase[(size_t)f * TT + (tt)] : 0.0f; \
        } } while (0)
        LDX(0, xA);
        LDX(1, xB);
        for (int k = 0; k < 125; ++k) {
            const int tb = k * 8;
#pragma unroll
            for (int s = 0; s < 8; ++s) {
                const int t = tb + s;
                float* xb = (s & 1) ? xB : xA;
                half8 a0;
#pragma unroll
                for (int j = 0; j < 8; ++j) a0[j] = (_Float16)xb[j];
                float4v acc[4];
#pragma unroll
                for (int g = 0; g < 4; ++g)
                    acc[g] = __builtin_amdgcn_mfma_f32_16x16x32_f16(a0, wf[g][0], biasC[g], 0, 0, 0);
                if ((s & 3) == 0) SPIN(ldmin4(flags + 4) >= t - 5);   // in1 slot reuse
                SPIN(ldmin4(flags + 8) >= t - 1);                     // siblings tight
                const _Float16* rd = in0 + s * SL0;
                half8 a1 = *(const half8*)(rd + arow + 32);
                half8 a2 = *(const half8*)(rd + arow + 64);
#pragma unroll
                for (int g = 0; g < 4; ++g)
                    acc[g] = __builtin_amdgcn_mfma_f32_16x16x32_f16(a1, wf[g][1], acc[g], 0, 0, 0);
#pragma unroll
                for (int g = 0; g < 4; ++g)
                    acc[g] = __builtin_amdgcn_mfma_f32_16x16x32_f16(a2, wf[g][2], acc[g], 0, 0, 0);
                float z[4];
#pragma unroll
                for (int g = 0; g < 4; ++g) z[g] = sel4(acc[g], q);
                float h = gate_update(z, c);
                _Float16 hf = (_Float16)h;
                in0[((s + 1) & 7) * SL0 + b * S0 + 32 + u] = hf; // own rec
                in1[s * SL1 + b * S1 + u]                  = hf; // L1 input
                DSFENCE();
                if (l == 0) vfl[8 + w4] = t;
                LDX((t + 2 < TT) ? (t + 2) : (TT - 1), xb);      // refill just-freed buf
            }
        }
#undef LDX
    } else {                            // ===== L1 (role==1) / L2 (role==0) =====
        _Float16* rin  = role ? in1 : in2;
        _Float16* rout = role ? in2 : nullptr;
        const int* pin = role ? (flags + 8) : (flags + 4);  // input producer group
        const int* pow_ = role ? (flags + 4) : (flags + 0); // own group
        for (int k = 0; k < 125; ++k) {
            const int tb = k * 8;
#pragma unroll
            for (int s = 0; s < 8; ++s) {
                const int t = tb + s;
                if ((s & 3) == 0) {
                    if (role) SPIN(ldmin4(pin) >= t + 3 && ldmin4(flags + 0) >= t - 5);
                    else      SPIN(ldmin4(pin) >= t + 3);
                }
                const _Float16* rd = rin + s * SL1;
                // input tiles: cross-lead guarantees slot t is >=3 ticks old
                half8 a0 = *(const half8*)(rd + arow);
                half8 a1 = *(const half8*)(rd + arow + 32);
                float4v acc[4];
#pragma unroll
                for (int g = 0; g < 4; ++g)
                    acc[g] = __builtin_amdgcn_mfma_f32_16x16x32_f16(a0, wf[g][0], biasC[g], 0, 0, 0);
#pragma unroll
                for (int g = 0; g < 4; ++g)
                    acc[g] = __builtin_amdgcn_mfma_f32_16x16x32_f16(a1, wf[g][1], acc[g], 0, 0, 0);
                SPIN(ldmin4(pow_) >= t - 1);                    // siblings tight
                half8 a2 = *(const half8*)(rd + arow + 64);     // rec tiles
                half8 a3 = *(const half8*)(rd + arow + 96);
#pragma unroll
                for (int g = 0; g < 4; ++g)
                    acc[g] = __builtin_amdgcn_mfma_f32_16x16x32_f16(a2, wf[g][2], acc[g], 0, 0, 0);
#pragma unroll
                for (int g = 0; g < 4; ++g)
                    acc[g] = __builtin_amdgcn_mfma_f32_16x16x32_f16(a3, wf[g][3], acc[g], 0, 0, 0);
                float z[4];
#pragma unroll
                for (int g = 0; g < 4; ++g) z[g] = sel4(acc[g], q);
                float h = gate_update(z, c);
                _Float16 hf = (_Float16)h;
                if (role) {
                    rin[((s + 1) & 7) * SL1 + b * S1 + 64 + u] = hf; // own rec
                    rout[s * SL1 + b * S1 + u]                 = hf; // L2 input
                } else {
                    if (t != TT - 1) rin[((s + 1) & 7) * SL1 + b * S1 + 64 + u] = hf;
                    else             fcA[b * 64 + u] = h;            // final h2 (fp32)
                }
                DSFENCE();
                if (l == 0) vfl[(role ? 4 : 0) + w4] = t;
            }
        }
    }

    __syncthreads();

    // ================= FC head (fp32) =================
    for (int i = tid; i < 54 * 64; i += 768) fcW[(i >> 6) * 65 + (i & 63)] = w0[i];
    for (int i = tid; i < 54; i += 768) {
        fcP[i] = b0[i]; fcP[64 + i] = g0[i]; fcP[128 + i] = be0[i];
        fcP[192 + i] = m0[i]; fcP[256 + i] = v0[i];
    }
    __syncthreads();
    for (int idx = tid; idx < BB * 54; idx += 768) {
        const int bb = idx / 54, j = idx - bb * 54;
        float s = fcP[j];
        for (int k = 0; k < 64; ++k) s += fcW[j * 65 + k] * fcA[bb * 64 + k];
        s = (s - fcP[192 + j]) * rsqrtf(fcP[256 + j] + 1e-5f) * fcP[64 + j] + fcP[128 + j];
        fcB[bb * 64 + j] = fmaxf(s, 0.0f);
    }
    __syncthreads();

    for (int i = tid; i < 44 * 54; i += 768) fcW[(i / 54) * 55 + (i % 54)] = w1[i];
    for (int i = tid; i < 44; i += 768) {
        fcP[i] = b1[i]; fcP[64 + i] = g1[i]; fcP[128 + i] = be1[i];
        fcP[192 + i] = m1[i]; fcP[256 + i] = v1[i];
    }
    __syncthreads();
    for (int idx = tid; idx < BB * 44; idx += 768) {
        const int bb = idx / 44, j = idx - bb * 44;
        float s = fcP[j];
        for (int k = 0; k < 54; ++k) s += fcW[j * 55 + k] * fcB[bb * 64 + k];
        s = (s - fcP[192 + j]) * rsqrtf(fcP[256 + j] + 1e-5f) * fcP[64 + j] + fcP[128 + j];
        fcA[bb * 64 + j] = fmaxf(s, 0.0f);
    }
    __syncthreads();

    for (int i = tid; i < 24 * 44; i += 768) fcW[(i / 44) * 45 + (i % 44)] = w2[i];
    for (int i = tid; i < 24; i += 768) {
        fcP[i] = b2[i]; fcP[64 + i] = g2[i]; fcP[128 + i] = be2[i];
        fcP[192 + i] = m2[i]; fcP[256 + i] = v2[i];
    }
    __syncthreads();
    for (int idx = tid; idx < BB * 24; idx += 768) {
        const int bb = idx / 24, j = idx - bb * 24;
        float s = fcP[j];
        for (int k = 0; k < 44; ++k) s += fcW[j * 45 + k] * fcA[bb * 64 + k];
        s = (s - fcP[192 + j]) * rsqrtf(fcP[256 + j] + 1e-5f) * fcP[64 + j] + fcP[128 + j];
        fcB[bb * 64 + j] = fmaxf(s, 0.0f);
    }
    __syncthreads();

    for (int i = tid; i < 4 * 24; i += 768) fcW[(i / 24) * 25 + (i % 24)] = w3[i];
    for (int i = tid; i < 4; i += 768) fcP[i] = b3[i];
    __syncthreads();
    for (int idx = tid; idx < BB * 4; idx += 768) {
        const int bb = idx / 4, j = idx - bb * 4;
        float s = fcP[j];
        for (int k = 0; k < 24; ++k) s += fcW[j * 25 + k] * fcB[bb * 64 + k];
        out[(size_t)(n0 + bb) * 4 + j] = s;
    }
}

extern "C" void kernel_launch(void* const* d_in, const int* in_sizes, int n_in,
                              void* d_out, int out_size, void* d_ws, size_t ws_size,
                              hipStream_t stream) {
    const float* p[33];
    for (int i = 0; i < 33; ++i) p[i] = (const float*)d_in[i];
    lstm_fused<<<NBLK, 768, 0, stream>>>(
        p[0],
        p[1], p[2], p[3], p[4],
        p[5], p[6], p[7], p[8],
        p[9], p[10], p[11], p[12],
        p[13], p[14], p[15], p[16], p[17], p[18], p[19], p[20],
        p[21], p[22], p[23], p[24],
        p[25], p[26], p[27], p[28],
        p[29], p[30], p[31], p[32],
        (float*)d_out);
}